// Round 4
// baseline (262.092 us; speedup 1.0000x reference)
//
#include <hip/hip_runtime.h>
#include <math.h>

#define CCH 256
#define CROP 7
#define NCELL (CROP * CROP)

typedef float vfloat4 __attribute__((ext_vector_type(4)));

__global__ __launch_bounds__(256) void roi_align_kernel(
    const float4* __restrict__ boxes,   // (B*N) float4; reference reads cols as [r1, c1, r2, c2]
    const float* __restrict__ f0,
    const float* __restrict__ f1,
    const float* __restrict__ f2,
    const float* __restrict__ f3,
    const float* __restrict__ f4,
    const int*  __restrict__ image_shape,
    float* __restrict__ out,
    int N)                              // boxes per batch image
{
    const int bn   = blockIdx.x;        // 0..B*N-1
    const int lane = threadIdx.x & 63;  // channel group: 4 floats each
    const int wv   = threadIdx.x >> 6;  // 0..3
    const int b    = bn / N;

    const float4 box = boxes[bn];
    // Reference: y1,x1,y2,x2 = boxes[:,0..3]  (row from cols 0/2, col from cols 1/3)
    const float ry1 = box.x;
    const float cx1 = box.y;
    const float ry2 = box.z;
    const float cx2 = box.w;

    const float h = cx2 - cx1;
    const float w = ry2 - ry1;

    const float area  = (float)(image_shape[0] * image_shape[1]);
    const float canon = 56.0f / sqrtf(area);
    const float lvlf  = log2f(sqrtf(h * w) / canon);
    int lvl = (int)rintf(lvlf);         // half-to-even, matches jnp.round
    lvl = lvl < 0 ? 0 : (lvl > 4 ? 4 : lvl);

    const float* f; int s;
    if      (lvl == 0) { f = f0; s = 256; }
    else if (lvl == 1) { f = f1; s = 128; }
    else if (lvl == 2) { f = f2; s = 64;  }
    else if (lvl == 3) { f = f3; s = 32;  }
    else               { f = f4; s = 16;  }

    const float Hf = (float)(s - 1);
    const float Wf = Hf;

    const float ystep = (ry2 - ry1) * Hf / 6.0f;
    const float xstep = (cx2 - cx1) * Wf / 6.0f;

    const size_t img = (size_t)b * s * s * CCH;
    vfloat4* outb = (vfloat4*)(out + (size_t)bn * NCELL * CCH);

    for (int cell = wv; cell < NCELL; cell += 4) {
        const int iy = cell / CROP;
        const int ix = cell - iy * CROP;

        const float ys = ry1 * Hf + (float)iy * ystep;
        const float xs = cx1 * Wf + (float)ix * xstep;

        const float y0f = floorf(ys);
        const float x0f = floorf(xs);
        const float ly = ys - y0f;
        const float lx = xs - x0f;

        const int y0  = (int)fminf(fmaxf(y0f,        0.0f), Hf);
        const int y1i = (int)fminf(fmaxf(y0f + 1.0f, 0.0f), Hf);
        const int x0  = (int)fminf(fmaxf(x0f,        0.0f), Wf);
        const int x1i = (int)fminf(fmaxf(x0f + 1.0f, 0.0f), Wf);

        const bool ok = (ys >= 0.0f) && (ys <= Hf) && (xs >= 0.0f) && (xs <= Wf);

        const float4 v00 = *((const float4*)(f + img + ((size_t)y0  * s + x0 ) * CCH) + lane);
        const float4 v01 = *((const float4*)(f + img + ((size_t)y0  * s + x1i) * CCH) + lane);
        const float4 v10 = *((const float4*)(f + img + ((size_t)y1i * s + x0 ) * CCH) + lane);
        const float4 v11 = *((const float4*)(f + img + ((size_t)y1i * s + x1i) * CCH) + lane);

        vfloat4 val;
        {
            float tx = v00.x + lx * (v01.x - v00.x);
            float bx = v10.x + lx * (v11.x - v10.x);
            val.x = tx + ly * (bx - tx);
            float ty = v00.y + lx * (v01.y - v00.y);
            float by = v10.y + lx * (v11.y - v10.y);
            val.y = ty + ly * (by - ty);
            float tz = v00.z + lx * (v01.z - v00.z);
            float bz = v10.z + lx * (v11.z - v10.z);
            val.z = tz + ly * (bz - tz);
            float tw = v00.w + lx * (v01.w - v00.w);
            float bw = v10.w + lx * (v11.w - v10.w);
            val.w = tw + ly * (bw - tw);
        }
        if (!ok) { val.x = 0.0f; val.y = 0.0f; val.z = 0.0f; val.w = 0.0f; }

        __builtin_nontemporal_store(val, outb + (size_t)cell * 64 + lane);
    }
}

extern "C" void kernel_launch(void* const* d_in, const int* in_sizes, int n_in,
                              void* d_out, int out_size, void* d_ws, size_t ws_size,
                              hipStream_t stream) {
    const float4* boxes = (const float4*)d_in[0];
    const float*  f0    = (const float*)d_in[1];
    const float*  f1    = (const float*)d_in[2];
    const float*  f2    = (const float*)d_in[3];
    const float*  f3    = (const float*)d_in[4];
    const float*  f4    = (const float*)d_in[5];
    const int*    ishp  = (const int*)d_in[6];
    float*        out   = (float*)d_out;

    const int BN = in_sizes[0] / 4;                    // B*N
    const int B  = in_sizes[1] / (256 * 256 * 256);    // from feat0
    const int N  = BN / B;

    roi_align_kernel<<<BN, 256, 0, stream>>>(boxes, f0, f1, f2, f3, f4, ishp, out, N);
}

// Round 5
// 262.079 us; speedup vs baseline: 1.0000x; 1.0000x over previous
//
#include <hip/hip_runtime.h>
#include <math.h>

#define CCH 256
#define CROP 7
#define NCELL (CROP * CROP)

__global__ __launch_bounds__(256) void roi_align_kernel(
    const float4* __restrict__ boxes,   // (B*N) float4; reference reads cols as [r1, c1, r2, c2]
    const float* __restrict__ f0,
    const float* __restrict__ f1,
    const float* __restrict__ f2,
    const float* __restrict__ f3,
    const float* __restrict__ f4,
    const int*  __restrict__ image_shape,
    float* __restrict__ out,
    int N)                              // boxes per batch image
{
    const int bn   = blockIdx.x;        // 0..B*N-1
    const int lane = threadIdx.x & 63;  // channel group: 4 floats each
    const int wv   = threadIdx.x >> 6;  // 0..3
    const int b    = bn / N;

    const float4 box = boxes[bn];
    // Reference: y1,x1,y2,x2 = boxes[:,0..3]  (row from cols 0/2, col from cols 1/3)
    const float ry1 = box.x;
    const float cx1 = box.y;
    const float ry2 = box.z;
    const float cx2 = box.w;

    const float h = cx2 - cx1;
    const float w = ry2 - ry1;

    const float area  = (float)(image_shape[0] * image_shape[1]);
    const float canon = 56.0f / sqrtf(area);
    const float lvlf  = log2f(sqrtf(h * w) / canon);
    int lvl = (int)rintf(lvlf);         // half-to-even, matches jnp.round
    lvl = lvl < 0 ? 0 : (lvl > 4 ? 4 : lvl);

    const float* f; int s;
    if      (lvl == 0) { f = f0; s = 256; }
    else if (lvl == 1) { f = f1; s = 128; }
    else if (lvl == 2) { f = f2; s = 64;  }
    else if (lvl == 3) { f = f3; s = 32;  }
    else               { f = f4; s = 16;  }

    const float Hf = (float)(s - 1);
    const float Wf = Hf;

    const float ystep = (ry2 - ry1) * Hf / 6.0f;
    const float xstep = (cx2 - cx1) * Wf / 6.0f;

    const size_t img = (size_t)b * s * s * CCH;
    float4* outb = (float4*)(out + (size_t)bn * NCELL * CCH);

    #pragma unroll 2
    for (int cell = wv; cell < NCELL; cell += 4) {
        const int iy = cell / CROP;
        const int ix = cell - iy * CROP;

        const float ys = ry1 * Hf + (float)iy * ystep;
        const float xs = cx1 * Wf + (float)ix * xstep;

        const float y0f = floorf(ys);
        const float x0f = floorf(xs);
        const float ly = ys - y0f;
        const float lx = xs - x0f;

        const int y0  = (int)fminf(fmaxf(y0f,        0.0f), Hf);
        const int y1i = (int)fminf(fmaxf(y0f + 1.0f, 0.0f), Hf);
        const int x0  = (int)fminf(fmaxf(x0f,        0.0f), Wf);
        const int x1i = (int)fminf(fmaxf(x0f + 1.0f, 0.0f), Wf);

        const bool ok = (ys >= 0.0f) && (ys <= Hf) && (xs >= 0.0f) && (xs <= Wf);

        const float4 v00 = *((const float4*)(f + img + ((size_t)y0  * s + x0 ) * CCH) + lane);
        const float4 v01 = *((const float4*)(f + img + ((size_t)y0  * s + x1i) * CCH) + lane);
        const float4 v10 = *((const float4*)(f + img + ((size_t)y1i * s + x0 ) * CCH) + lane);
        const float4 v11 = *((const float4*)(f + img + ((size_t)y1i * s + x1i) * CCH) + lane);

        float4 val;
        {
            float tx = v00.x + lx * (v01.x - v00.x);
            float bx = v10.x + lx * (v11.x - v10.x);
            val.x = tx + ly * (bx - tx);
            float ty = v00.y + lx * (v01.y - v00.y);
            float by = v10.y + lx * (v11.y - v10.y);
            val.y = ty + ly * (by - ty);
            float tz = v00.z + lx * (v01.z - v00.z);
            float bz = v10.z + lx * (v11.z - v10.z);
            val.z = tz + ly * (bz - tz);
            float tw = v00.w + lx * (v01.w - v00.w);
            float bw = v10.w + lx * (v11.w - v10.w);
            val.w = tw + ly * (bw - tw);
        }
        if (!ok) { val.x = 0.0f; val.y = 0.0f; val.z = 0.0f; val.w = 0.0f; }

        outb[(size_t)cell * 64 + lane] = val;
    }
}

extern "C" void kernel_launch(void* const* d_in, const int* in_sizes, int n_in,
                              void* d_out, int out_size, void* d_ws, size_t ws_size,
                              hipStream_t stream) {
    const float4* boxes = (const float4*)d_in[0];
    const float*  f0    = (const float*)d_in[1];
    const float*  f1    = (const float*)d_in[2];
    const float*  f2    = (const float*)d_in[3];
    const float*  f3    = (const float*)d_in[4];
    const float*  f4    = (const float*)d_in[5];
    const int*    ishp  = (const int*)d_in[6];
    float*        out   = (float*)d_out;

    const int BN = in_sizes[0] / 4;                    // B*N
    const int B  = in_sizes[1] / (256 * 256 * 256);    // from feat0
    const int N  = BN / B;

    roi_align_kernel<<<BN, 256, 0, stream>>>(boxes, f0, f1, f2, f3, f4, ishp, out, N);
}